// Round 1
// baseline (2666.392 us; speedup 1.0000x reference)
//
#include <hip/hip_runtime.h>
#include <math.h>

// Problem constants
#define BB   16
#define NP   196
#define HH   4
#define KVD  960
#define NPART 16

#define BM 128
#define BN 128
#define BK 16

static __host__ __device__ inline int divup(int a, int b) { return (a + b - 1) / b; }

// ---------------------------------------------------------------------------
// NT GEMM: C[M,Nn] = alpha * A[M,Kk] * B[Nn,Kk]^T   (all row-major)
// Batched: z -> (bb = z / Hdiv, hh = z % Hdiv); ptr += bb*s?b + hh*s?h
// ---------------------------------------------------------------------------
__global__ __launch_bounds__(256)
void gemm_nt_kernel(const float* __restrict__ A, const float* __restrict__ B,
                    float* __restrict__ C, int M, int Nn, int Kk,
                    long sAb, long sAh, long sBb, long sBh, long sCb, long sCh,
                    int Hdiv, float alpha)
{
    int z = blockIdx.z;
    int bb = z / Hdiv, hh = z % Hdiv;
    A += (long)bb * sAb + (long)hh * sAh;
    B += (long)bb * sBb + (long)hh * sBh;
    C += (long)bb * sCb + (long)hh * sCh;

    __shared__ float As[BK][BM + 4];
    __shared__ float Bs[BK][BN + 4];

    int t  = threadIdx.x;
    int m0 = blockIdx.y * BM, n0 = blockIdx.x * BN;
    int lr = t >> 2;            // 0..63
    int lk = (t & 3) * 4;       // 0,4,8,12
    int tx = t & 15, ty = t >> 4;

    float acc[8][8];
#pragma unroll
    for (int i = 0; i < 8; i++)
#pragma unroll
        for (int j = 0; j < 8; j++) acc[i][j] = 0.f;

    int nkt = divup(Kk, BK);
    for (int kt = 0; kt < nkt; ++kt) {
        int k0 = kt * BK;
        // load A tile [BM x BK], store transposed As[k][m]
#pragma unroll
        for (int rr = 0; rr < 2; rr++) {
            int m = lr + rr * 64;
            float4 v = make_float4(0.f, 0.f, 0.f, 0.f);
            if (m0 + m < M && k0 + lk < Kk)
                v = *(const float4*)(A + (long)(m0 + m) * Kk + k0 + lk);
            As[lk + 0][m] = v.x; As[lk + 1][m] = v.y;
            As[lk + 2][m] = v.z; As[lk + 3][m] = v.w;
        }
        // load B tile [BN x BK] (rows are output cols), store transposed Bs[k][n]
#pragma unroll
        for (int rr = 0; rr < 2; rr++) {
            int n = lr + rr * 64;
            float4 v = make_float4(0.f, 0.f, 0.f, 0.f);
            if (n0 + n < Nn && k0 + lk < Kk)
                v = *(const float4*)(B + (long)(n0 + n) * Kk + k0 + lk);
            Bs[lk + 0][n] = v.x; Bs[lk + 1][n] = v.y;
            Bs[lk + 2][n] = v.z; Bs[lk + 3][n] = v.w;
        }
        __syncthreads();
#pragma unroll
        for (int k = 0; k < BK; k++) {
            float a[8], b[8];
            *(float4*)&a[0] = *(const float4*)&As[k][ty * 4];
            *(float4*)&a[4] = *(const float4*)&As[k][64 + ty * 4];
            *(float4*)&b[0] = *(const float4*)&Bs[k][tx * 4];
            *(float4*)&b[4] = *(const float4*)&Bs[k][64 + tx * 4];
#pragma unroll
            for (int i = 0; i < 8; i++)
#pragma unroll
                for (int j = 0; j < 8; j++)
                    acc[i][j] = fmaf(a[i], b[j], acc[i][j]);
        }
        __syncthreads();
    }
    // epilogue: rows {ty*4..+3, 64+ty*4..+3}, cols {tx*4..+3, 64+tx*4..+3}
#pragma unroll
    for (int i = 0; i < 8; i++) {
        int m = m0 + ((i < 4) ? (ty * 4 + i) : (64 + ty * 4 + i - 4));
        if (m >= M) continue;
        float* cr = C + (long)m * Nn;
#pragma unroll
        for (int jh = 0; jh < 2; jh++) {
            int n = n0 + jh * 64 + tx * 4;
            if (n < Nn) {
                float4 v;
                v.x = alpha * acc[i][jh * 4 + 0];
                v.y = alpha * acc[i][jh * 4 + 1];
                v.z = alpha * acc[i][jh * 4 + 2];
                v.w = alpha * acc[i][jh * 4 + 3];
                *(float4*)(cr + n) = v;
            }
        }
    }
}

// ---------------------------------------------------------------------------
// NN GEMM: C[M,Nn] = alpha * A[M,Kk] * B[Kk,Nn]   (all row-major)
// Batched on z with single strides.
// ---------------------------------------------------------------------------
__global__ __launch_bounds__(256)
void gemm_nn_kernel(const float* __restrict__ A, const float* __restrict__ B,
                    float* __restrict__ C, int M, int Nn, int Kk,
                    long sAb, long sBb, long sCb, float alpha)
{
    int z = blockIdx.z;
    A += (long)z * sAb;
    B += (long)z * sBb;
    C += (long)z * sCb;

    __shared__ float As[BK][BM + 4];
    __shared__ float Bs[BK][BN + 4];

    int t  = threadIdx.x;
    int m0 = blockIdx.y * BM, n0 = blockIdx.x * BN;
    int alr = t >> 2, alk = (t & 3) * 4;
    int bkr = t >> 5, bnc = (t & 31) * 4;
    int tx = t & 15, ty = t >> 4;

    float acc[8][8];
#pragma unroll
    for (int i = 0; i < 8; i++)
#pragma unroll
        for (int j = 0; j < 8; j++) acc[i][j] = 0.f;

    int nkt = divup(Kk, BK);
    for (int kt = 0; kt < nkt; ++kt) {
        int k0 = kt * BK;
#pragma unroll
        for (int rr = 0; rr < 2; rr++) {
            int m = alr + rr * 64;
            float4 v = make_float4(0.f, 0.f, 0.f, 0.f);
            if (m0 + m < M && k0 + alk < Kk)
                v = *(const float4*)(A + (long)(m0 + m) * Kk + k0 + alk);
            As[alk + 0][m] = v.x; As[alk + 1][m] = v.y;
            As[alk + 2][m] = v.z; As[alk + 3][m] = v.w;
        }
#pragma unroll
        for (int rr = 0; rr < 2; rr++) {
            int k = bkr + rr * 8;
            float4 v = make_float4(0.f, 0.f, 0.f, 0.f);
            if (k0 + k < Kk && n0 + bnc < Nn)
                v = *(const float4*)(B + (long)(k0 + k) * Nn + n0 + bnc);
            *(float4*)&Bs[k][bnc] = v;
        }
        __syncthreads();
#pragma unroll
        for (int k = 0; k < BK; k++) {
            float a[8], b[8];
            *(float4*)&a[0] = *(const float4*)&As[k][ty * 4];
            *(float4*)&a[4] = *(const float4*)&As[k][64 + ty * 4];
            *(float4*)&b[0] = *(const float4*)&Bs[k][tx * 4];
            *(float4*)&b[4] = *(const float4*)&Bs[k][64 + tx * 4];
#pragma unroll
            for (int i = 0; i < 8; i++)
#pragma unroll
                for (int j = 0; j < 8; j++)
                    acc[i][j] = fmaf(a[i], b[j], acc[i][j]);
        }
        __syncthreads();
    }
#pragma unroll
    for (int i = 0; i < 8; i++) {
        int m = m0 + ((i < 4) ? (ty * 4 + i) : (64 + ty * 4 + i - 4));
        if (m >= M) continue;
        float* cr = C + (long)m * Nn;
#pragma unroll
        for (int jh = 0; jh < 2; jh++) {
            int n = n0 + jh * 64 + tx * 4;
            if (n < Nn) {
                float4 v;
                v.x = alpha * acc[i][jh * 4 + 0];
                v.y = alpha * acc[i][jh * 4 + 1];
                v.z = alpha * acc[i][jh * 4 + 2];
                v.w = alpha * acc[i][jh * 4 + 3];
                *(float4*)(cr + n) = v;
            }
        }
    }
}

// ---------------------------------------------------------------------------
// stats: per map (blockIdx.y) partial sum/sumsq over elems; NPART blocks/map.
// ---------------------------------------------------------------------------
__global__ __launch_bounds__(256)
void stats_kernel(const float* __restrict__ S, int elems, long map_stride,
                  double* __restrict__ part)
{
    int mapl = blockIdx.y;
    const float* p = S + (size_t)mapl * map_stride;
    double s1 = 0.0, s2 = 0.0;
    for (int i = blockIdx.x * 256 + threadIdx.x; i < elems; i += NPART * 256) {
        double v = (double)p[i];
        s1 += v; s2 += v * v;
    }
    __shared__ double sh1[256], sh2[256];
    int t = threadIdx.x;
    sh1[t] = s1; sh2[t] = s2;
    __syncthreads();
    for (int off = 128; off > 0; off >>= 1) {
        if (t < off) { sh1[t] += sh1[t + off]; sh2[t] += sh2[t + off]; }
        __syncthreads();
    }
    if (t == 0) {
        part[((size_t)mapl * NPART + blockIdx.x) * 2 + 0] = sh1[0];
        part[((size_t)mapl * NPART + blockIdx.x) * 2 + 1] = sh2[0];
    }
}

// ---------------------------------------------------------------------------
// softmax over a row of kv entries, scaled by inv_std of the map.
// InstanceNorm mean cancels in softmax; only inv_std matters.
// grid: (rows=c, maps=g). In-place on S.
// ---------------------------------------------------------------------------
__global__ __launch_bounds__(256)
void softmax_kernel(float* __restrict__ S, const double* __restrict__ part,
                    int kv, long map_stride, float inv_elems)
{
    int mapl = blockIdx.y;
    int row  = blockIdx.x;
    int t    = threadIdx.x;

    __shared__ float red[4];
    __shared__ float s_is;
    if (t == 0) {
        const double* pp = part + (size_t)mapl * NPART * 2;
        double s1 = 0.0, s2 = 0.0;
        for (int i = 0; i < NPART; i++) { s1 += pp[2 * i]; s2 += pp[2 * i + 1]; }
        float mean = (float)(s1 * (double)inv_elems);
        float var  = (float)(s2 * (double)inv_elems) - mean * mean;
        s_is = rsqrtf(var + 1e-5f);
    }
    __syncthreads();
    float is = s_is;

    float* p = S + (size_t)mapl * map_stride + (size_t)row * kv;
    float v[4];
    float mx = -3.0e38f;
#pragma unroll
    for (int i = 0; i < 4; i++) {
        int col = t + i * 256;
        v[i] = (col < kv) ? p[col] : -3.0e38f;
        mx = fmaxf(mx, v[i]);
    }
#pragma unroll
    for (int off = 32; off > 0; off >>= 1) mx = fmaxf(mx, __shfl_down(mx, off));
    if ((t & 63) == 0) red[t >> 6] = mx;
    __syncthreads();
    float bm = fmaxf(fmaxf(red[0], red[1]), fmaxf(red[2], red[3]));

    float e[4], ssum = 0.f;
#pragma unroll
    for (int i = 0; i < 4; i++) {
        int col = t + i * 256;
        e[i] = (col < kv) ? expf((v[i] - bm) * is) : 0.f;
        ssum += e[i];
    }
#pragma unroll
    for (int off = 32; off > 0; off >>= 1) ssum += __shfl_down(ssum, off);
    __syncthreads();   // everyone done reading red (max)
    if ((t & 63) == 0) red[t >> 6] = ssum;
    __syncthreads();
    float Z  = red[0] + red[1] + red[2] + red[3];
    float rz = 1.0f / Z;
#pragma unroll
    for (int i = 0; i < 4; i++) {
        int col = t + i * 256;
        if (col < kv) p[col] = e[i] * rz;
    }
}

// ---------------------------------------------------------------------------
// mean over heads + transpose: Mb[b,n,d] = 0.25 * sum_h Cb[(b*4+h), d, n]
// grid: (divup(196,32), c/32, 16), block 256 (tx=0..31, ty=0..7)
// ---------------------------------------------------------------------------
__global__ __launch_bounds__(256)
void mean_t_kernel(const float* __restrict__ Cb, float* __restrict__ Mb, int c)
{
    int b  = blockIdx.z;
    int n0 = blockIdx.x * 32;
    int d0 = blockIdx.y * 32;
    __shared__ float tile[32][33];
    int tx = threadIdx.x & 31;
    int ty = threadIdx.x >> 5;
#pragma unroll
    for (int i = 0; i < 4; i++) {
        int d = d0 + ty + i * 8;
        int n = n0 + tx;
        float s = 0.f;
        if (n < NP) {
#pragma unroll
            for (int h = 0; h < HH; h++)
                s += Cb[(((long)(b * HH + h)) * c + d) * NP + n];
        }
        tile[ty + i * 8][tx] = 0.25f * s;
    }
    __syncthreads();
#pragma unroll
    for (int i = 0; i < 4; i++) {
        int n = n0 + ty + i * 8;
        int d = d0 + tx;
        if (n < NP)
            Mb[((long)b * NP + n) * c + d] = tile[tx][ty + i * 8];
    }
}

// ---------------------------------------------------------------------------
extern "C" void kernel_launch(void* const* d_in, const int* in_sizes, int n_in,
                              void* d_out, int out_size, void* d_ws, size_t ws_size,
                              hipStream_t stream)
{
    const float* emb[4]  = {(const float*)d_in[0], (const float*)d_in[1],
                            (const float*)d_in[2], (const float*)d_in[3]};
    const float* emb_all = (const float*)d_in[4];
    const float* Wq[4]   = {(const float*)d_in[5], (const float*)d_in[6],
                            (const float*)d_in[7], (const float*)d_in[8]};
    const float* Wk = (const float*)d_in[9];
    const float* Wv = (const float*)d_in[10];
    const float* Wo[4]   = {(const float*)d_in[11], (const float*)d_in[12],
                            (const float*)d_in[13], (const float*)d_in[14]};
    float* out = (float*)d_out;

    const int Cc[4] = {64, 128, 256, 512};

    // ---- workspace carve (256B aligned) ----
    char* base = (char*)d_ws;
    size_t off = 0;
    auto carve = [&](size_t bytes) -> char* {
        char* p = base + off;
        off = (off + bytes + 255) & ~(size_t)255;
        return p;
    };
    float*  Kbuf = (float*) carve((size_t)64 * NP * KVD * 4);    // [bh][196][960]
    float*  Vt   = (float*) carve((size_t)64 * KVD * NP * 4);    // [bh][960][196]
    float*  Qb   = (float*) carve((size_t)64 * 512 * NP * 4);    // [bh][c][196]
    float*  Cb   = (float*) carve((size_t)64 * 512 * NP * 4);    // [bh][c][196]
    float*  Mb   = (float*) carve((size_t)BB * NP * 512 * 4);    // [b][196][c]
    double* part = (double*)carve((size_t)64 * NPART * 2 * 8);
    size_t savail = (ws_size > off) ? (ws_size - off) : 0;
    float* Sb = (float*)(base + off);                            // [g][c][960]

    dim3 blk(256);
    const float alphaS = 1.0f / sqrtf((float)KVD);

    // K[b,h] = emb_all[b] @ Wk[h]^T  -> [196, 960]
    {
        dim3 g(divup(KVD, BN), divup(NP, BM), 64);
        gemm_nt_kernel<<<g, blk, 0, stream>>>(emb_all, Wk, Kbuf, NP, KVD, KVD,
            (long)NP * KVD, 0, 0, (long)KVD * KVD,
            (long)HH * NP * KVD, (long)NP * KVD, HH, 1.0f);
    }
    // Vt[b,h] = Wv[h] @ emb_all[b]^T -> [960, 196]
    {
        dim3 g(divup(NP, BN), divup(KVD, BM), 64);
        gemm_nt_kernel<<<g, blk, 0, stream>>>(Wv, emb_all, Vt, KVD, NP, KVD,
            0, (long)KVD * KVD, (long)NP * KVD, 0,
            (long)HH * KVD * NP, (long)KVD * NP, HH, 1.0f);
    }

    long ooff = 0;
    for (int i = 0; i < 4; i++) {
        int c = Cc[i];
        // Qt[b,h] = Wq_i[h] @ emb_i[b]^T -> [c, 196]
        {
            dim3 g(divup(NP, BN), divup(c, BM), 64);
            gemm_nt_kernel<<<g, blk, 0, stream>>>(Wq[i], emb[i], Qb, c, NP, c,
                0, (long)c * c, (long)NP * c, 0,
                (long)HH * c * NP, (long)c * NP, HH, 1.0f);
        }
        size_t mapbytes = (size_t)c * KVD * 4;
        int G = (int)((savail >= mapbytes) ? (savail / mapbytes) : 1);
        if (G > 64) G = 64;
        if (G < 1)  G = 1;
        for (int m0 = 0; m0 < 64; m0 += G) {
            int g = (64 - m0 < G) ? (64 - m0) : G;
            // S = (Qt @ K) / sqrt(KV)   [c, 960]
            {
                dim3 gr(divup(KVD, BN), divup(c, BM), g);
                gemm_nn_kernel<<<gr, blk, 0, stream>>>(
                    Qb + (size_t)m0 * c * NP, Kbuf + (size_t)m0 * NP * KVD, Sb,
                    c, KVD, NP, (long)c * NP, (long)NP * KVD, (long)c * KVD, alphaS);
            }
            // var over each [c,960] map (mean cancels in softmax)
            {
                dim3 gr(NPART, g);
                stats_kernel<<<gr, blk, 0, stream>>>(Sb, c * KVD, (long)c * KVD, part);
            }
            // row softmax with inv_std scale, in-place -> P
            {
                dim3 gr(c, g);
                softmax_kernel<<<gr, blk, 0, stream>>>(Sb, part, KVD, (long)c * KVD,
                                                       1.0f / (float)(c * KVD));
            }
            // ctx = P @ Vt   [c, 196]
            {
                dim3 gr(divup(NP, BN), divup(c, BM), g);
                gemm_nn_kernel<<<gr, blk, 0, stream>>>(
                    Sb, Vt + (size_t)m0 * KVD * NP, Cb + (size_t)m0 * c * NP,
                    c, NP, KVD, (long)c * KVD, (long)KVD * NP, (long)c * NP, 1.0f);
            }
        }
        // head-mean + transpose -> Mb[b,n,d]
        {
            dim3 gr(divup(NP, 32), c / 32, BB);
            mean_t_kernel<<<gr, blk, 0, stream>>>(Cb, Mb, c);
        }
        // O = Mb @ Wo^T  (M = B*N = 3136)
        {
            dim3 gr(divup(c, BN), divup(BB * NP, BM), 1);
            gemm_nt_kernel<<<gr, blk, 0, stream>>>(Mb, Wo[i], out + ooff,
                BB * NP, c, c, 0, 0, 0, 0, 0, 0, 1, 1.0f);
        }
        ooff += (long)BB * NP * c;
    }
}

// Round 3
// 2261.857 us; speedup vs baseline: 1.1789x; 1.1789x over previous
//
#include <hip/hip_runtime.h>
#include <math.h>

#define BB 16
#define NP 196
#define HH 4
#define KVD 960
#define NPART 16
#define LDP 200   // padded leading dim for n=196-contiguous rows (200*2B = 400B, 16B-aligned)

typedef __attribute__((ext_vector_type(8))) short s8v;
typedef __attribute__((ext_vector_type(8))) unsigned short u8v;
typedef __attribute__((ext_vector_type(4))) unsigned short u4v;
typedef __attribute__((ext_vector_type(4))) float f4v;

static inline int divup(int a, int b){ return (a+b-1)/b; }
static inline int imin(int a, int b){ return a < b ? a : b; }

__device__ __forceinline__ unsigned short bf16r(float x){
    unsigned int u = __float_as_uint(x);
    u += 0x7fffu + ((u >> 16) & 1u);       // round-to-nearest-even
    return (unsigned short)(u >> 16);
}
__device__ __forceinline__ float bf16f(unsigned short h){
    return __uint_as_float(((unsigned int)h) << 16);
}

// ---------------------------------------------------------------------------
// decompose fp32 -> (hi, lo) bf16 pair: x = hi + lo + O(2^-17 x)
// ---------------------------------------------------------------------------
__global__ __launch_bounds__(256)
void decomp_kernel(const float* __restrict__ x, unsigned short* __restrict__ hi,
                   unsigned short* __restrict__ lo, long n4)
{
    for (long i = (long)blockIdx.x * 256 + threadIdx.x; i < n4; i += (long)gridDim.x * 256) {
        float4 v = ((const float4*)x)[i];
        float a[4] = {v.x, v.y, v.z, v.w};
        u4v h, l;
#pragma unroll
        for (int e = 0; e < 4; e++) {
            unsigned short hb = bf16r(a[e]);
            h[e] = hb;
            l[e] = bf16r(a[e] - bf16f(hb));
        }
        *(u4v*)(hi + i * 4) = h;
        *(u4v*)(lo + i * 4) = l;
    }
}

// ---------------------------------------------------------------------------
// Split-bf16 NT GEMM via MFMA: C[M,Nn] = alpha * A[M,Kk] * B[Nn,Kk]^T
// A,B are bf16 (hi,lo) pairs, row-major K-contiguous. 3-term split product
// (AhBh + AlBh + AhBl) accumulated in fp32 AGPRs -> ~fp32-GEMM accuracy.
// OSPLIT=1: write C as bf16 (hi,lo) pair; else fp32.
// Batched on z: bb=z/Hdiv, hh=z%Hdiv, operand offsets via strides.
// Tile 128x128xK32, 4 waves (2x2), each wave 64x64 = 4x4 frags of 16x16x32.
// LDS row: 128B = 8 x 16B slots [4 hi k-chunks | 4 lo], slot XOR-swizzled by r&7.
// ---------------------------------------------------------------------------
template<int OSPLIT>
__global__ __launch_bounds__(256)
void gemm_split(const unsigned short* __restrict__ Ah, const unsigned short* __restrict__ Al,
                const unsigned short* __restrict__ Bh, const unsigned short* __restrict__ Bl,
                float* __restrict__ Cf, unsigned short* __restrict__ Ch,
                unsigned short* __restrict__ Cl,
                int M, int Nn, int Kk, int ldA, int ldB, int ldC,
                long sAb, long sAh_, long sBb, long sBh_, long sCb, long sCh_,
                int Hdiv, float alpha)
{
    __shared__ u8v AsV[128 * 8];
    __shared__ u8v BsV[128 * 8];
    unsigned short* As = (unsigned short*)AsV;
    unsigned short* Bs = (unsigned short*)BsV;

    int z  = blockIdx.z;
    int bb = z / Hdiv, hz = z - bb * Hdiv;
    const unsigned short* gah = Ah + (long)bb * sAb + (long)hz * sAh_;
    const unsigned short* gal = Al + (long)bb * sAb + (long)hz * sAh_;
    const unsigned short* gbh = Bh + (long)bb * sBb + (long)hz * sBh_;
    const unsigned short* gbl = Bl + (long)bb * sBb + (long)hz * sBh_;
    long coff = (long)bb * sCb + (long)hz * sCh_;

    int t = threadIdx.x;
    int m0 = blockIdx.y * 128, n0 = blockIdx.x * 128;
    int wave = t >> 6, lane = t & 63;
    int wm = wave >> 1, wn = wave & 1;
    int lr = lane & 15, lk = lane >> 4;

    f4v acc[4][4];
#pragma unroll
    for (int i = 0; i < 4; i++)
#pragma unroll
        for (int j = 0; j < 4; j++) acc[i][j] = (f4v){0.f, 0.f, 0.f, 0.f};

    int nkt = (Kk + 31) >> 5;
    for (int kt = 0; kt < nkt; ++kt) {
        int k0 = kt << 5;
#pragma unroll
        for (int half = 0; half < 2; ++half) {
            const unsigned short* Gh = half ? gbh : gah;
            const unsigned short* Gl = half ? gbl : gal;
            unsigned short* Sm = half ? Bs : As;
            int rows = half ? Nn : M;
            int rbase = half ? n0 : m0;
            int ld = half ? ldB : ldA;
#pragma unroll
            for (int it = 0; it < 4; ++it) {
                int cid  = t + it * 256;
                int comp = cid >> 9;          // 0=hi 1=lo
                int r    = (cid >> 2) & 127;  // tile row
                int s    = cid & 3;           // 8-elem k-chunk
                const unsigned short* G = comp ? Gl : Gh;
                int gr = rbase + r;
                int gk = k0 + s * 8;
                u8v v = {0, 0, 0, 0, 0, 0, 0, 0};
                if (gr < rows) {
                    if (gk + 8 <= Kk) {
                        v = *(const u8v*)(G + (long)gr * ld + gk);
                    } else if (gk < Kk) {
#pragma unroll
                        for (int e = 0; e < 8; e++)
                            if (gk + e < Kk) v[e] = G[(long)gr * ld + gk + e];
                    }
                }
                int slot = s + comp * 4;
                *(u8v*)&Sm[r * 64 + ((slot ^ (r & 7)) << 3)] = v;
            }
        }
        __syncthreads();

        s8v afh[4], afl[4], bfh[4], bfl[4];
#pragma unroll
        for (int i = 0; i < 4; i++) {
            int rw = wm * 64 + i * 16 + lr;
            afh[i] = *(const s8v*)&As[rw * 64 + ((lk ^ (rw & 7)) << 3)];
            afl[i] = *(const s8v*)&As[rw * 64 + (((lk + 4) ^ (rw & 7)) << 3)];
            int cw = wn * 64 + i * 16 + lr;
            bfh[i] = *(const s8v*)&Bs[cw * 64 + ((lk ^ (cw & 7)) << 3)];
            bfl[i] = *(const s8v*)&Bs[cw * 64 + (((lk + 4) ^ (cw & 7)) << 3)];
        }
#pragma unroll
        for (int i = 0; i < 4; i++)
#pragma unroll
            for (int j = 0; j < 4; j++) {
                acc[i][j] = __builtin_amdgcn_mfma_f32_16x16x32_bf16(afh[i], bfh[j], acc[i][j], 0, 0, 0);
                acc[i][j] = __builtin_amdgcn_mfma_f32_16x16x32_bf16(afl[i], bfh[j], acc[i][j], 0, 0, 0);
                acc[i][j] = __builtin_amdgcn_mfma_f32_16x16x32_bf16(afh[i], bfl[j], acc[i][j], 0, 0, 0);
            }
        __syncthreads();
    }

    // epilogue: C/D layout col=lane&15, row=(lane>>4)*4+reg  [m89-verified]
#pragma unroll
    for (int i = 0; i < 4; i++)
#pragma unroll
        for (int j = 0; j < 4; j++)
#pragma unroll
            for (int r = 0; r < 4; r++) {
                int gr = m0 + wm * 64 + i * 16 + lk * 4 + r;
                int gc = n0 + wn * 64 + j * 16 + lr;
                if (gr < M && gc < Nn) {
                    float v = acc[i][j][r] * alpha;
                    if (OSPLIT) {
                        unsigned short hb = bf16r(v);
                        Ch[coff + (long)gr * ldC + gc] = hb;
                        Cl[coff + (long)gr * ldC + gc] = bf16r(v - bf16f(hb));
                    } else {
                        Cf[coff + (long)gr * ldC + gc] = v;
                    }
                }
            }
}

// ---------------------------------------------------------------------------
// stats: per-map partial sum/sumsq (fp64), NPART blocks per map.
// ---------------------------------------------------------------------------
__global__ __launch_bounds__(256)
void stats_kernel(const float* __restrict__ S, int elems, long map_stride,
                  double* __restrict__ part)
{
    int mapl = blockIdx.y;
    const float* p = S + (size_t)mapl * map_stride;
    double s1 = 0.0, s2 = 0.0;
    for (int i = blockIdx.x * 256 + threadIdx.x; i < elems; i += NPART * 256) {
        double v = (double)p[i];
        s1 += v; s2 += v * v;
    }
    __shared__ double sh1[256], sh2[256];
    int t = threadIdx.x;
    sh1[t] = s1; sh2[t] = s2;
    __syncthreads();
    for (int off = 128; off > 0; off >>= 1) {
        if (t < off) { sh1[t] += sh1[t + off]; sh2[t] += sh2[t + off]; }
        __syncthreads();
    }
    if (t == 0) {
        part[((size_t)mapl * NPART + blockIdx.x) * 2 + 0] = sh1[0];
        part[((size_t)mapl * NPART + blockIdx.x) * 2 + 1] = sh2[0];
    }
}

// ---------------------------------------------------------------------------
// row softmax with inv_std scale; writes P as bf16 (hi,lo) pair.
// InstanceNorm mean cancels in row softmax; only inv_std matters.
// ---------------------------------------------------------------------------
__global__ __launch_bounds__(256)
void softmax_kernel(const float* __restrict__ S, unsigned short* __restrict__ Ph,
                    unsigned short* __restrict__ Pl, const double* __restrict__ part,
                    long map_stride, float inv_elems)
{
    int mapl = blockIdx.y;
    int row  = blockIdx.x;
    int t    = threadIdx.x;

    __shared__ float red[4];
    __shared__ float s_is;
    if (t == 0) {
        const double* pp = part + (size_t)mapl * NPART * 2;
        double s1 = 0.0, s2 = 0.0;
        for (int i = 0; i < NPART; i++) { s1 += pp[2 * i]; s2 += pp[2 * i + 1]; }
        float mean = (float)(s1 * (double)inv_elems);
        float var  = (float)(s2 * (double)inv_elems) - mean * mean;
        s_is = rsqrtf(var + 1e-5f);
    }
    __syncthreads();
    float is = s_is;

    const float* p = S + (size_t)mapl * map_stride + (size_t)row * KVD;
    unsigned short* ph = Ph + (size_t)mapl * map_stride + (size_t)row * KVD;
    unsigned short* pl = Pl + (size_t)mapl * map_stride + (size_t)row * KVD;

    float v[4];
    float mx = -3.0e38f;
#pragma unroll
    for (int i = 0; i < 4; i++) {
        int col = t + i * 256;
        v[i] = (col < KVD) ? p[col] : -3.0e38f;
        mx = fmaxf(mx, v[i]);
    }
#pragma unroll
    for (int off = 32; off > 0; off >>= 1) mx = fmaxf(mx, __shfl_down(mx, off));
    if ((t & 63) == 0) red[t >> 6] = mx;
    __syncthreads();
    float bm = fmaxf(fmaxf(red[0], red[1]), fmaxf(red[2], red[3]));

    float e[4], ssum = 0.f;
#pragma unroll
    for (int i = 0; i < 4; i++) {
        int col = t + i * 256;
        e[i] = (col < KVD) ? expf((v[i] - bm) * is) : 0.f;
        ssum += e[i];
    }
#pragma unroll
    for (int off = 32; off > 0; off >>= 1) ssum += __shfl_down(ssum, off);
    __syncthreads();   // all lanes done reading red (max) before reuse
    if ((t & 63) == 0) red[t >> 6] = ssum;
    __syncthreads();
    float Z  = red[0] + red[1] + red[2] + red[3];
    float rz = 1.0f / Z;
#pragma unroll
    for (int i = 0; i < 4; i++) {
        int col = t + i * 256;
        if (col < KVD) {
            float pr = e[i] * rz;
            unsigned short hb = bf16r(pr);
            ph[col] = hb;
            pl[col] = bf16r(pr - bf16f(hb));
        }
    }
}

// ---------------------------------------------------------------------------
// head-mean + transpose: Mb[b,n,d] = 0.25 * sum_h Cb[(b*4+h), d, n], split out.
// b is group-local here.
// ---------------------------------------------------------------------------
__global__ __launch_bounds__(256)
void mean_t_kernel(const float* __restrict__ Cb, unsigned short* __restrict__ Mh,
                   unsigned short* __restrict__ Ml, int c)
{
    int b  = blockIdx.z;
    int n0 = blockIdx.x * 32;
    int d0 = blockIdx.y * 32;
    __shared__ float tile[32][33];
    int tx = threadIdx.x & 31;
    int ty = threadIdx.x >> 5;
#pragma unroll
    for (int i = 0; i < 4; i++) {
        int d = d0 + ty + i * 8;
        int n = n0 + tx;
        float s = 0.f;
        if (n < NP) {
#pragma unroll
            for (int h = 0; h < HH; h++)
                s += Cb[(((long)(b * HH + h)) * c + d) * NP + n];
        }
        tile[ty + i * 8][tx] = 0.25f * s;
    }
    __syncthreads();
#pragma unroll
    for (int i = 0; i < 4; i++) {
        int n = n0 + ty + i * 8;
        int d = d0 + tx;
        if (n < NP) {
            float val = tile[tx][ty + i * 8];
            long idx = ((long)b * NP + n) * c + d;
            unsigned short hb = bf16r(val);
            Mh[idx] = hb;
            Ml[idx] = bf16r(val - bf16f(hb));
        }
    }
}

// ---------------------------------------------------------------------------
extern "C" void kernel_launch(void* const* d_in, const int* in_sizes, int n_in,
                              void* d_out, int out_size, void* d_ws, size_t ws_size,
                              hipStream_t stream)
{
    const float* embf[4] = {(const float*)d_in[0], (const float*)d_in[1],
                            (const float*)d_in[2], (const float*)d_in[3]};
    const float* emb_all = (const float*)d_in[4];
    const float* Wq[4]   = {(const float*)d_in[5], (const float*)d_in[6],
                            (const float*)d_in[7], (const float*)d_in[8]};
    const float* Wk = (const float*)d_in[9];
    const float* Wv = (const float*)d_in[10];
    const float* Wo[4]   = {(const float*)d_in[11], (const float*)d_in[12],
                            (const float*)d_in[13], (const float*)d_in[14]};
    float* out = (float*)d_out;

    const int Cc[4] = {64, 128, 256, 512};

    char* base = (char*)d_ws;
    size_t off = 0;
    auto carve = [&](size_t bytes) -> void* {
        void* p = base + off;
        off = (off + bytes + 255) & ~(size_t)255;
        return p;
    };

    const long NEA   = (long)BB * NP * KVD;                       // 3,010,560
    const long NWKV  = (long)HH * KVD * KVD;                      // 3,686,400
    const long SUMC2 = 64L*64 + 128L*128 + 256L*256 + 512L*512;   // 349,440

    // ---- fixed buffers: split weights + split emb_all ----
    unsigned short* wkH = (unsigned short*)carve(NWKV * 2);
    unsigned short* wkL = (unsigned short*)carve(NWKV * 2);
    unsigned short* wvH = (unsigned short*)carve(NWKV * 2);
    unsigned short* wvL = (unsigned short*)carve(NWKV * 2);
    unsigned short* wqH = (unsigned short*)carve((long)HH * SUMC2 * 2);
    unsigned short* wqL = (unsigned short*)carve((long)HH * SUMC2 * 2);
    unsigned short* woH = (unsigned short*)carve(SUMC2 * 2);
    unsigned short* woL = (unsigned short*)carve(SUMC2 * 2);
    unsigned short* eaH = (unsigned short*)carve(NEA * 2);
    unsigned short* eaL = (unsigned short*)carve(NEA * 2);
    double* part = (double*)carve(64L * NPART * 2 * 8);

    // ---- adaptive batch grouping: GB batches per pass ----
    size_t fixed_off = off;
    auto group_bytes = [&](int gb) -> size_t {
        long nbh = (long)gb * HH;
        size_t s = 0;
        auto add = [&](size_t b){ s += (b + 255) & ~(size_t)255; };
        add(nbh * KVD * LDP * 2); add(nbh * KVD * LDP * 2);  // Kt hi/lo
        add(nbh * NP * KVD * 2);  add(nbh * NP * KVD * 2);   // V hi/lo
        add(nbh * 512 * LDP * 2); add(nbh * 512 * LDP * 2);  // Qt hi/lo
        add(nbh * 512 * NP * 4);                             // Cb fp32
        add((long)gb * NP * 512 * 2); add((long)gb * NP * 512 * 2); // ei hi/lo
        add((long)gb * NP * 512 * 2); add((long)gb * NP * 512 * 2); // Mb hi/lo
        return s;
    };
    const size_t minchunk = (size_t)512 * KVD * 8 + (1 << 20); // 1 S/P map @ c=512 + slack
    int GB = 16;
    while (GB > 1 && fixed_off + group_bytes(GB) + minchunk > ws_size) GB >>= 1;
    const long NBH = (long)GB * HH;   // maps per group

    unsigned short* KtH = (unsigned short*)carve(NBH * KVD * LDP * 2);
    unsigned short* KtL = (unsigned short*)carve(NBH * KVD * LDP * 2);
    unsigned short* VH  = (unsigned short*)carve(NBH * NP * KVD * 2);
    unsigned short* VL  = (unsigned short*)carve(NBH * NP * KVD * 2);
    unsigned short* QtH = (unsigned short*)carve(NBH * 512 * LDP * 2);
    unsigned short* QtL = (unsigned short*)carve(NBH * 512 * LDP * 2);
    float*  Cb          = (float*)carve(NBH * 512 * NP * 4);
    unsigned short* eiH = (unsigned short*)carve((long)GB * NP * 512 * 2);
    unsigned short* eiL = (unsigned short*)carve((long)GB * NP * 512 * 2);
    unsigned short* MbH = (unsigned short*)carve((long)GB * NP * 512 * 2);
    unsigned short* MbL = (unsigned short*)carve((long)GB * NP * 512 * 2);

    size_t savail = (ws_size > off) ? (ws_size - off) : 0;
    char* chunk = base + off;

    dim3 blk(256);
    const float alphaS = 1.0f / sqrtf((float)KVD);

    auto dec = [&](const float* x, unsigned short* h, unsigned short* l, long n) {
        long n4 = n / 4;
        int g = (int)((n4 + 255) / 256);
        if (g > 1024) g = 1024;
        decomp_kernel<<<g, blk, 0, stream>>>(x, h, l, n4);
    };

    // ---- decompose weights + emb_all once ----
    dec(emb_all, eaH, eaL, NEA);
    long wqo[4], woo[4];
    long qo = 0, oo = 0;
    for (int i = 0; i < 4; i++) {
        wqo[i] = qo; dec(Wq[i], wqH + qo, wqL + qo, (long)HH * Cc[i] * Cc[i]);
        qo += (long)HH * Cc[i] * Cc[i];
        woo[i] = oo; dec(Wo[i], woH + oo, woL + oo, (long)Cc[i] * Cc[i]);
        oo += (long)Cc[i] * Cc[i];
    }
    dec(Wk, wkH, wkL, NWKV);
    dec(Wv, wvH, wvL, NWKV);

    long obase[4];
    { long o = 0; for (int i = 0; i < 4; i++) { obase[i] = o; o += (long)BB * NP * Cc[i]; } }

    // ---- batch-group passes ----
    for (int g0 = 0; g0 < BB; g0 += GB) {
        const unsigned short* eaHg = eaH + (long)g0 * NP * KVD;
        const unsigned short* eaLg = eaL + (long)g0 * NP * KVD;

        // Kt[bh][960][LDP] = Wk[h] @ emb_all[b]^T
        gemm_split<1><<<dim3(divup(NP, 128), divup(KVD, 128), (int)NBH), blk, 0, stream>>>(
            wkH, wkL, eaHg, eaLg, nullptr, KtH, KtL,
            KVD, NP, KVD, KVD, KVD, LDP,
            0, (long)KVD * KVD, (long)NP * KVD, 0,
            (long)HH * KVD * LDP, (long)KVD * LDP, HH, 1.0f);

        // V[bh][196][960] = emb_all[b] @ Wv[h]^T
        gemm_split<1><<<dim3(divup(KVD, 128), divup(NP, 128), (int)NBH), blk, 0, stream>>>(
            eaHg, eaLg, wvH, wvL, nullptr, VH, VL,
            NP, KVD, KVD, KVD, KVD, KVD,
            (long)NP * KVD, 0, 0, (long)KVD * KVD,
            (long)HH * NP * KVD, (long)NP * KVD, HH, 1.0f);

        for (int i = 0; i < 4; i++) {
            int c = Cc[i];
            // decompose this group's emb_i
            dec(embf[i] + (long)g0 * NP * c, eiH, eiL, (long)GB * NP * c);

            // Qt[bh][c][LDP] = Wq_i[h] @ emb_i[b]^T
            gemm_split<1><<<dim3(divup(NP, 128), divup(c, 128), (int)NBH), blk, 0, stream>>>(
                wqH + wqo[i], wqL + wqo[i], eiH, eiL, nullptr, QtH, QtL,
                c, NP, c, c, c, LDP,
                0, (long)c * c, (long)NP * c, 0,
                (long)HH * c * LDP, (long)c * LDP, HH, 1.0f);

            size_t per = (size_t)c * KVD * 8;   // S fp32 + P hi/lo per map
            int G = (savail >= per) ? (int)(savail / per) : 1;
            if (G > (int)NBH) G = (int)NBH;
            if (G < 1) G = 1;
            float* Sb = (float*)chunk;
            unsigned short* PhB = (unsigned short*)(chunk + (size_t)G * c * KVD * 4);
            unsigned short* PlB = PhB + (size_t)G * c * KVD;

            for (int m0 = 0; m0 < (int)NBH; m0 += G) {
                int g = imin(G, (int)NBH - m0);
                // S[c,960] = (Qt @ Kt^T) / sqrt(960)
                gemm_split<0><<<dim3(divup(KVD, 128), divup(c, 128), g), blk, 0, stream>>>(
                    QtH + (size_t)m0 * c * LDP, QtL + (size_t)m0 * c * LDP,
                    KtH + (size_t)m0 * KVD * LDP, KtL + (size_t)m0 * KVD * LDP,
                    Sb, nullptr, nullptr,
                    c, KVD, NP, LDP, LDP, KVD,
                    (long)c * LDP, 0, (long)KVD * LDP, 0, (long)c * KVD, 0,
                    1, alphaS);
                // per-map var (InstanceNorm mean cancels in softmax)
                stats_kernel<<<dim3(NPART, g), blk, 0, stream>>>(Sb, c * KVD, (long)c * KVD, part);
                // softmax -> split P
                softmax_kernel<<<dim3(c, g), blk, 0, stream>>>(Sb, PhB, PlB, part,
                                                               (long)c * KVD, 1.0f / (float)(c * KVD));
                // ctx[c,196] = P @ V^T
                gemm_split<0><<<dim3(divup(NP, 128), divup(c, 128), g), blk, 0, stream>>>(
                    PhB, PlB, VH + (size_t)m0 * NP * KVD, VL + (size_t)m0 * NP * KVD,
                    Cb + (size_t)m0 * c * NP, nullptr, nullptr,
                    c, NP, KVD, KVD, KVD, NP,
                    (long)c * KVD, 0, (long)NP * KVD, 0, (long)c * NP, 0,
                    1, 1.0f);
            }
            // head-mean + transpose -> split Mb[b_local,n,d]
            mean_t_kernel<<<dim3(divup(NP, 32), c / 32, GB), blk, 0, stream>>>(Cb, MbH, MbL, c);
            // O rows for this group = Mb @ Wo^T
            gemm_split<0><<<dim3(divup(c, 128), divup(GB * NP, 128), 1), blk, 0, stream>>>(
                MbH, MbL, woH + woo[i], woL + woo[i],
                out + obase[i] + (long)g0 * NP * c, nullptr, nullptr,
                GB * NP, c, c, c, c, c,
                0, 0, 0, 0, 0, 0, 1, 1.0f);
        }
    }
}

// Round 4
// 1376.826 us; speedup vs baseline: 1.9366x; 1.6428x over previous
//
#include <hip/hip_runtime.h>
#include <math.h>

#define BB 16
#define NP 196
#define HH 4
#define KVD 960
#define KP 224    // K=196 padded to multiple of 32 for clean global_load_lds staging

typedef __attribute__((ext_vector_type(8))) short s8v;
typedef __attribute__((ext_vector_type(8))) unsigned short u8v;
typedef __attribute__((ext_vector_type(4))) unsigned short u4v;
typedef __attribute__((ext_vector_type(4))) float f4v;

static inline int divup(int a, int b){ return (a+b-1)/b; }
static inline int imin(int a, int b){ return a < b ? a : b; }

__device__ __forceinline__ unsigned short bf16r(float x){
    unsigned int u = __float_as_uint(x);
    u += 0x7fffu + ((u >> 16) & 1u);       // round-to-nearest-even
    return (unsigned short)(u >> 16);
}
__device__ __forceinline__ float bf16f(unsigned short h){
    return __uint_as_float(((unsigned int)h) << 16);
}

// async global->LDS, 16B per lane; LDS dest = uniform base + lane*16
__device__ __forceinline__ void gload16(const unsigned short* g, unsigned short* l){
    __builtin_amdgcn_global_load_lds(
        (const __attribute__((address_space(1))) void*)g,
        (__attribute__((address_space(3))) void*)l, 16, 0, 0);
}

// ---------------------------------------------------------------------------
// decompose fp32 -> (hi, lo) bf16 pair: x = hi + lo + O(2^-17 x)
// ---------------------------------------------------------------------------
__global__ __launch_bounds__(256)
void decomp_kernel(const float* __restrict__ x, unsigned short* __restrict__ hi,
                   unsigned short* __restrict__ lo, long n4)
{
    for (long i = (long)blockIdx.x * 256 + threadIdx.x; i < n4; i += (long)gridDim.x * 256) {
        float4 v = ((const float4*)x)[i];
        float a[4] = {v.x, v.y, v.z, v.w};
        u4v h, l;
#pragma unroll
        for (int e = 0; e < 4; e++) {
            unsigned short hb = bf16r(a[e]);
            h[e] = hb;
            l[e] = bf16r(a[e] - bf16f(hb));
        }
        *(u4v*)(hi + i * 4) = h;
        *(u4v*)(lo + i * 4) = l;
    }
}

// ---------------------------------------------------------------------------
// Split-bf16 NT GEMM via MFMA: C[M,Nn] = alpha * A[M,Kk] * B[Nn,Kk]^T
// A,B are bf16 (hi,lo) pairs, row-major K-contiguous; Kk % 32 == 0.
// Staging: global_load_lds dwordx4, LINEAR LDS dest, pre-swizzled global src
//   (logical slot ls = (lane&7)^(lane>>3); comp=ls>>2 picks hi/lo buffer).
// LDS row: 128B = 8 x 16B slots, logical slot s stored at s ^ (row&7).
// Rows beyond M/Nn are clamped (contributions masked at store).
// OSPLIT=1: write C as bf16 (hi,lo) pair, zero pad cols [Nn,ldC).
// STATS=1: accumulate per-map sum/sumsq of alpha-scaled C into part[z*2..]
// Tile 128x128xK32, 4 waves (2x2), each wave 64x64 = 4x4 frags of 16x16x32.
// ---------------------------------------------------------------------------
template<int OSPLIT, int STATS>
__global__ __launch_bounds__(256)
void gemm_split(const unsigned short* __restrict__ Ah, const unsigned short* __restrict__ Al,
                const unsigned short* __restrict__ Bh, const unsigned short* __restrict__ Bl,
                float* __restrict__ Cf, unsigned short* __restrict__ Ch,
                unsigned short* __restrict__ Cl, double* __restrict__ part,
                int M, int Nn, int Kk, int ldA, int ldB, int ldC,
                long sAb, long sAh_, long sBb, long sBh_, long sCb, long sCh_,
                int Hdiv, float alpha)
{
    __shared__ u8v AsV[128 * 8];
    __shared__ u8v BsV[128 * 8];
    unsigned short* As = (unsigned short*)AsV;
    unsigned short* Bs = (unsigned short*)BsV;

    int z  = blockIdx.z;
    int bb = z / Hdiv, hz = z - bb * Hdiv;
    const unsigned short* gah = Ah + (long)bb * sAb + (long)hz * sAh_;
    const unsigned short* gal = Al + (long)bb * sAb + (long)hz * sAh_;
    const unsigned short* gbh = Bh + (long)bb * sBb + (long)hz * sBh_;
    const unsigned short* gbl = Bl + (long)bb * sBb + (long)hz * sBh_;
    long coff = (long)bb * sCb + (long)hz * sCh_;

    int t = threadIdx.x;
    int m0 = blockIdx.y * 128, n0 = blockIdx.x * 128;
    int wave = t >> 6, lane = t & 63;
    int wm = wave >> 1, wn = wave & 1;
    int lr = lane & 15, lk = lane >> 4;

    // ---- staging address precompute (pre-swizzled global source) ----
    int ls   = (lane & 7) ^ (lane >> 3);   // logical slot at this lane's linear LDS spot
    int comp = ls >> 2;                    // 0 = hi, 1 = lo
    int chnk = ls & 3;                     // 8-elem k-chunk within component
    const unsigned short* gA = comp ? gal : gah;
    const unsigned short* gB = comp ? gbl : gbh;
    const unsigned short* aptr[4];
    const unsigned short* bptr[4];
#pragma unroll
    for (int j = 0; j < 4; j++) {
        int ra = m0 + wave * 32 + j * 8 + (lane >> 3);
        ra = (ra < M) ? ra : (M - 1);
        aptr[j] = gA + (long)ra * ldA + chnk * 8;
        int rb = n0 + wave * 32 + j * 8 + (lane >> 3);
        rb = (rb < Nn) ? rb : (Nn - 1);
        bptr[j] = gB + (long)rb * ldB + chnk * 8;
    }

    f4v acc[4][4];
#pragma unroll
    for (int i = 0; i < 4; i++)
#pragma unroll
        for (int j = 0; j < 4; j++) acc[i][j] = (f4v){0.f, 0.f, 0.f, 0.f};

    int nkt = Kk >> 5;
    for (int kt = 0; kt < nkt; ++kt) {
        int k0 = kt << 5;
#pragma unroll
        for (int j = 0; j < 4; j++) {
            gload16(aptr[j] + k0, As + (wave * 4 + j) * 512);
            gload16(bptr[j] + k0, Bs + (wave * 4 + j) * 512);
        }
        __syncthreads();

        s8v afh[4], afl[4], bfh[4], bfl[4];
#pragma unroll
        for (int i = 0; i < 4; i++) {
            int rw = wm * 64 + i * 16 + lr;
            afh[i] = *(const s8v*)&As[rw * 64 + ((lk ^ (rw & 7)) << 3)];
            afl[i] = *(const s8v*)&As[rw * 64 + (((lk + 4) ^ (rw & 7)) << 3)];
            int cw = wn * 64 + i * 16 + lr;
            bfh[i] = *(const s8v*)&Bs[cw * 64 + ((lk ^ (cw & 7)) << 3)];
            bfl[i] = *(const s8v*)&Bs[cw * 64 + (((lk + 4) ^ (cw & 7)) << 3)];
        }
#pragma unroll
        for (int i = 0; i < 4; i++)
#pragma unroll
            for (int j = 0; j < 4; j++) {
                acc[i][j] = __builtin_amdgcn_mfma_f32_16x16x32_bf16(afh[i], bfh[j], acc[i][j], 0, 0, 0);
                acc[i][j] = __builtin_amdgcn_mfma_f32_16x16x32_bf16(afl[i], bfh[j], acc[i][j], 0, 0, 0);
                acc[i][j] = __builtin_amdgcn_mfma_f32_16x16x32_bf16(afh[i], bfl[j], acc[i][j], 0, 0, 0);
            }
        __syncthreads();
    }

    // epilogue: C/D layout col=lane&15, row=(lane>>4)*4+reg  [m89-verified]
    float s1 = 0.f, s2 = 0.f;
#pragma unroll
    for (int i = 0; i < 4; i++)
#pragma unroll
        for (int j = 0; j < 4; j++)
#pragma unroll
            for (int r = 0; r < 4; r++) {
                int gr = m0 + wm * 64 + i * 16 + lk * 4 + r;
                int gc = n0 + wn * 64 + j * 16 + lr;
                if (gr < M) {
                    if (gc < Nn) {
                        float v = acc[i][j][r] * alpha;
                        if (STATS) { s1 += v; s2 += v * v; }
                        if (OSPLIT) {
                            unsigned short hb = bf16r(v);
                            Ch[coff + (long)gr * ldC + gc] = hb;
                            Cl[coff + (long)gr * ldC + gc] = bf16r(v - bf16f(hb));
                        } else {
                            Cf[coff + (long)gr * ldC + gc] = v;
                        }
                    } else if (OSPLIT && gc < ldC) {   // zero K-pad columns
                        Ch[coff + (long)gr * ldC + gc] = 0;
                        Cl[coff + (long)gr * ldC + gc] = 0;
                    }
                }
            }

    if (STATS) {
        double* sh = (double*)AsV;   // reuse LDS (all waves past final barrier)
        sh[t] = (double)s1; sh[256 + t] = (double)s2;
        __syncthreads();
        for (int o = 128; o > 0; o >>= 1) {
            if (t < o) { sh[t] += sh[t + o]; sh[256 + t] += sh[256 + t + o]; }
            __syncthreads();
        }
        if (t == 0) {
            atomicAdd(&part[z * 2 + 0], sh[0]);
            atomicAdd(&part[z * 2 + 1], sh[256]);
        }
    }
}

// ---------------------------------------------------------------------------
// row softmax with inv_std scale; writes P as bf16 (hi,lo) pair.
// InstanceNorm mean cancels in row softmax; only inv_std matters.
// ---------------------------------------------------------------------------
__global__ __launch_bounds__(256)
void softmax_kernel(const float* __restrict__ S, unsigned short* __restrict__ Ph,
                    unsigned short* __restrict__ Pl, const double* __restrict__ part,
                    long map_stride, float inv_elems)
{
    int mapl = blockIdx.y;
    int row  = blockIdx.x;
    int t    = threadIdx.x;

    __shared__ float red[4];
    __shared__ float s_is;
    if (t == 0) {
        double su = part[mapl * 2 + 0], sq = part[mapl * 2 + 1];
        float mean = (float)(su * (double)inv_elems);
        float var  = (float)(sq * (double)inv_elems) - mean * mean;
        s_is = rsqrtf(var + 1e-5f);
    }
    __syncthreads();
    float is = s_is;

    const float* p = S + (size_t)mapl * map_stride + (size_t)row * KVD;
    unsigned short* ph = Ph + (size_t)mapl * map_stride + (size_t)row * KVD;
    unsigned short* pl = Pl + (size_t)mapl * map_stride + (size_t)row * KVD;

    float v[4];
    float mx = -3.0e38f;
#pragma unroll
    for (int i = 0; i < 4; i++) {
        int col = t + i * 256;
        v[i] = (col < KVD) ? p[col] : -3.0e38f;
        mx = fmaxf(mx, v[i]);
    }
#pragma unroll
    for (int off = 32; off > 0; off >>= 1) mx = fmaxf(mx, __shfl_down(mx, off));
    if ((t & 63) == 0) red[t >> 6] = mx;
    __syncthreads();
    float bm = fmaxf(fmaxf(red[0], red[1]), fmaxf(red[2], red[3]));

    float e[4], ssum = 0.f;
#pragma unroll
    for (int i = 0; i < 4; i++) {
        int col = t + i * 256;
        e[i] = (col < KVD) ? expf((v[i] - bm) * is) : 0.f;
        ssum += e[i];
    }
#pragma unroll
    for (int off = 32; off > 0; off >>= 1) ssum += __shfl_down(ssum, off);
    __syncthreads();
    if ((t & 63) == 0) red[t >> 6] = ssum;
    __syncthreads();
    float Z  = red[0] + red[1] + red[2] + red[3];
    float rz = 1.0f / Z;
#pragma unroll
    for (int i = 0; i < 4; i++) {
        int col = t + i * 256;
        if (col < KVD) {
            float pr = e[i] * rz;
            unsigned short hb = bf16r(pr);
            ph[col] = hb;
            pl[col] = bf16r(pr - bf16f(hb));
        }
    }
}

// ---------------------------------------------------------------------------
// head-mean + transpose: Mb[b,n,d] = 0.25 * sum_h Cb[(b*4+h), d, n], split out.
// ---------------------------------------------------------------------------
__global__ __launch_bounds__(256)
void mean_t_kernel(const float* __restrict__ Cb, unsigned short* __restrict__ Mh,
                   unsigned short* __restrict__ Ml, int c)
{
    int b  = blockIdx.z;
    int n0 = blockIdx.x * 32;
    int d0 = blockIdx.y * 32;
    __shared__ float tile[32][33];
    int tx = threadIdx.x & 31;
    int ty = threadIdx.x >> 5;
#pragma unroll
    for (int i = 0; i < 4; i++) {
        int d = d0 + ty + i * 8;
        int n = n0 + tx;
        float s = 0.f;
        if (n < NP) {
#pragma unroll
            for (int h = 0; h < HH; h++)
                s += Cb[(((long)(b * HH + h)) * c + d) * NP + n];
        }
        tile[ty + i * 8][tx] = 0.25f * s;
    }
    __syncthreads();
#pragma unroll
    for (int i = 0; i < 4; i++) {
        int n = n0 + ty + i * 8;
        int d = d0 + tx;
        if (n < NP) {
            float val = tile[tx][ty + i * 8];
            long idx = ((long)b * NP + n) * c + d;
            unsigned short hb = bf16r(val);
            Mh[idx] = hb;
            Ml[idx] = bf16r(val - bf16f(hb));
        }
    }
}

// ---------------------------------------------------------------------------
extern "C" void kernel_launch(void* const* d_in, const int* in_sizes, int n_in,
                              void* d_out, int out_size, void* d_ws, size_t ws_size,
                              hipStream_t stream)
{
    const float* embf[4] = {(const float*)d_in[0], (const float*)d_in[1],
                            (const float*)d_in[2], (const float*)d_in[3]};
    const float* emb_all = (const float*)d_in[4];
    const float* Wq[4]   = {(const float*)d_in[5], (const float*)d_in[6],
                            (const float*)d_in[7], (const float*)d_in[8]};
    const float* Wk = (const float*)d_in[9];
    const float* Wv = (const float*)d_in[10];
    const float* Wo[4]   = {(const float*)d_in[11], (const float*)d_in[12],
                            (const float*)d_in[13], (const float*)d_in[14]};
    float* out = (float*)d_out;

    const int Cc[4] = {64, 128, 256, 512};

    char* base = (char*)d_ws;
    size_t off = 0;
    auto carve = [&](size_t bytes) -> void* {
        void* p = base + off;
        off = (off + bytes + 255) & ~(size_t)255;
        return p;
    };

    const long NEA   = (long)BB * NP * KVD;                       // 3,010,560
    const long NWKV  = (long)HH * KVD * KVD;                      // 3,686,400
    const long SUMC2 = 64L*64 + 128L*128 + 256L*256 + 512L*512;   // 349,440

    // ---- fixed buffers: split weights + split emb_all ----
    unsigned short* wkH = (unsigned short*)carve(NWKV * 2);
    unsigned short* wkL = (unsigned short*)carve(NWKV * 2);
    unsigned short* wvH = (unsigned short*)carve(NWKV * 2);
    unsigned short* wvL = (unsigned short*)carve(NWKV * 2);
    unsigned short* wqH = (unsigned short*)carve((long)HH * SUMC2 * 2);
    unsigned short* wqL = (unsigned short*)carve((long)HH * SUMC2 * 2);
    unsigned short* woH = (unsigned short*)carve(SUMC2 * 2);
    unsigned short* woL = (unsigned short*)carve(SUMC2 * 2);
    unsigned short* eaH = (unsigned short*)carve(NEA * 2);
    unsigned short* eaL = (unsigned short*)carve(NEA * 2);
    double* part = (double*)carve(64L * 2 * 8);

    // ---- adaptive batch grouping: GB batches per pass ----
    size_t fixed_off = off;
    auto group_bytes = [&](int gb) -> size_t {
        long nbh = (long)gb * HH;
        size_t s = 0;
        auto add = [&](size_t b){ s += (b + 255) & ~(size_t)255; };
        add(nbh * KVD * KP * 2); add(nbh * KVD * KP * 2);    // Kt hi/lo
        add(nbh * NP * KVD * 2); add(nbh * NP * KVD * 2);    // V hi/lo
        add(nbh * 512 * KP * 2); add(nbh * 512 * KP * 2);    // Qt hi/lo
        add(nbh * 512 * NP * 4);                             // Cb fp32
        add((long)gb * NP * 512 * 2); add((long)gb * NP * 512 * 2); // ei hi/lo
        add((long)gb * NP * 512 * 2); add((long)gb * NP * 512 * 2); // Mb hi/lo
        return s;
    };
    const size_t minchunk = (size_t)512 * KVD * 8 + (1 << 20); // 1 S/P map @ c=512 + slack
    int GB = 16;
    while (GB > 1 && fixed_off + group_bytes(GB) + minchunk > ws_size) GB >>= 1;
    const long NBH = (long)GB * HH;   // maps per group

    unsigned short* KtH = (unsigned short*)carve(NBH * KVD * KP * 2);
    unsigned short* KtL = (unsigned short*)carve(NBH * KVD * KP * 2);
    unsigned short* VH  = (unsigned short*)carve(NBH * NP * KVD * 2);
    unsigned short* VL  = (unsigned short*)carve(NBH * NP * KVD * 2);
    unsigned short* QtH = (unsigned short*)carve(NBH * 512 * KP * 2);
    unsigned short* QtL = (unsigned short*)carve(NBH * 512 * KP * 2);
    float*  Cb          = (float*)carve(NBH * 512 * NP * 4);
    unsigned short* eiH = (unsigned short*)carve((long)GB * NP * 512 * 2);
    unsigned short* eiL = (unsigned short*)carve((long)GB * NP * 512 * 2);
    unsigned short* MbH = (unsigned short*)carve((long)GB * NP * 512 * 2);
    unsigned short* MbL = (unsigned short*)carve((long)GB * NP * 512 * 2);

    size_t savail = (ws_size > off) ? (ws_size - off) : 0;
    char* chunk = base + off;

    dim3 blk(256);
    const float alphaS = 1.0f / sqrtf((float)KVD);

    auto dec = [&](const float* x, unsigned short* h, unsigned short* l, long n) {
        long n4 = n / 4;
        int g = (int)((n4 + 255) / 256);
        if (g > 1024) g = 1024;
        decomp_kernel<<<g, blk, 0, stream>>>(x, h, l, n4);
    };

    // ---- decompose weights + emb_all once ----
    dec(emb_all, eaH, eaL, NEA);
    long wqo[4], woo[4];
    long qo = 0, oo = 0;
    for (int i = 0; i < 4; i++) {
        wqo[i] = qo; dec(Wq[i], wqH + qo, wqL + qo, (long)HH * Cc[i] * Cc[i]);
        qo += (long)HH * Cc[i] * Cc[i];
        woo[i] = oo; dec(Wo[i], woH + oo, woL + oo, (long)Cc[i] * Cc[i]);
        oo += (long)Cc[i] * Cc[i];
    }
    dec(Wk, wkH, wkL, NWKV);
    dec(Wv, wvH, wvL, NWKV);

    long obase[4];
    { long o = 0; for (int i = 0; i < 4; i++) { obase[i] = o; o += (long)BB * NP * Cc[i]; } }

    // ---- batch-group passes ----
    for (int g0 = 0; g0 < BB; g0 += GB) {
        const unsigned short* eaHg = eaH + (long)g0 * NP * KVD;
        const unsigned short* eaLg = eaL + (long)g0 * NP * KVD;

        // Kt[bh][960][KP] = Wk[h] @ emb_all[b]^T   (pad cols zeroed)
        gemm_split<1,0><<<dim3(divup(NP, 128), divup(KVD, 128), (int)NBH), blk, 0, stream>>>(
            wkH, wkL, eaHg, eaLg, nullptr, KtH, KtL, nullptr,
            KVD, NP, KVD, KVD, KVD, KP,
            0, (long)KVD * KVD, (long)NP * KVD, 0,
            (long)HH * KVD * KP, (long)KVD * KP, HH, 1.0f);

        // V[bh][196][960] = emb_all[b] @ Wv[h]^T
        gemm_split<1,0><<<dim3(divup(KVD, 128), divup(NP, 128), (int)NBH), blk, 0, stream>>>(
            eaHg, eaLg, wvH, wvL, nullptr, VH, VL, nullptr,
            NP, KVD, KVD, KVD, KVD, KVD,
            (long)NP * KVD, 0, 0, (long)KVD * KVD,
            (long)HH * NP * KVD, (long)NP * KVD, HH, 1.0f);

        for (int i = 0; i < 4; i++) {
            int c = Cc[i];
            dec(embf[i] + (long)g0 * NP * c, eiH, eiL, (long)GB * NP * c);

            // Qt[bh][c][KP] = Wq_i[h] @ emb_i[b]^T   (pad cols zeroed)
            gemm_split<1,0><<<dim3(divup(NP, 128), divup(c, 128), (int)NBH), blk, 0, stream>>>(
                wqH + wqo[i], wqL + wqo[i], eiH, eiL, nullptr, QtH, QtL, nullptr,
                c, NP, c, c, c, KP,
                0, (long)c * c, (long)NP * c, 0,
                (long)HH * c * KP, (long)c * KP, HH, 1.0f);

            size_t per = (size_t)c * KVD * 8;   // S fp32 + P hi/lo per map
            int G = (savail >= per) ? (int)(savail / per) : 1;
            if (G > (int)NBH) G = (int)NBH;
            if (G < 1) G = 1;
            float* Sb = (float*)chunk;
            unsigned short* PhB = (unsigned short*)(chunk + (size_t)G * c * KVD * 4);
            unsigned short* PlB = PhB + (size_t)G * c * KVD;

            for (int m0 = 0; m0 < (int)NBH; m0 += G) {
                int g = imin(G, (int)NBH - m0);
                hipMemsetAsync(part, 0, (size_t)g * 2 * sizeof(double), stream);
                // S[c,960] = (Qt @ Kt^T)/sqrt(960), K padded to 224; fused stats
                gemm_split<0,1><<<dim3(divup(KVD, 128), divup(c, 128), g), blk, 0, stream>>>(
                    QtH + (size_t)m0 * c * KP, QtL + (size_t)m0 * c * KP,
                    KtH + (size_t)m0 * KVD * KP, KtL + (size_t)m0 * KVD * KP,
                    Sb, nullptr, nullptr, part,
                    c, KVD, KP, KP, KP, KVD,
                    (long)c * KP, 0, (long)KVD * KP, 0, (long)c * KVD, 0,
                    1, alphaS);
                // softmax (scaled by per-map inv_std) -> split P
                softmax_kernel<<<dim3(c, g), blk, 0, stream>>>(Sb, PhB, PlB, part,
                                                               (long)c * KVD, 1.0f / (float)(c * KVD));
                // ctx[c,196] = P @ V^T
                gemm_split<0,0><<<dim3(divup(NP, 128), divup(c, 128), g), blk, 0, stream>>>(
                    PhB, PlB, VH + (size_t)m0 * NP * KVD, VL + (size_t)m0 * NP * KVD,
                    Cb + (size_t)m0 * c * NP, nullptr, nullptr, nullptr,
                    c, NP, KVD, KVD, KVD, NP,
                    (long)c * KVD, 0, (long)NP * KVD, 0, (long)c * NP, 0,
                    1, 1.0f);
            }
            // head-mean + transpose -> split Mb[b_local,n,d]
            mean_t_kernel<<<dim3(divup(NP, 32), c / 32, GB), blk, 0, stream>>>(Cb, MbH, MbL, c);
            // O rows for this group = Mb @ Wo^T
            gemm_split<0,0><<<dim3(divup(c, 128), divup(GB * NP, 128), 1), blk, 0, stream>>>(
                MbH, MbL, woH + woo[i], woL + woo[i],
                out + obase[i] + (long)g0 * NP * c, nullptr, nullptr, nullptr,
                GB * NP, c, c, c, c, c,
                0, 0, 0, 0, 0, 0, 1, 1.0f);
        }
    }
}

// Round 5
// 1081.121 us; speedup vs baseline: 2.4663x; 1.2735x over previous
//
#include <hip/hip_runtime.h>
#include <math.h>

#define BB 16
#define NP 196
#define HH 4
#define KVD 960
#define KP 224    // K=196 padded to multiple of 32 for clean global_load_lds staging

typedef __attribute__((ext_vector_type(8))) short s8v;
typedef __attribute__((ext_vector_type(8))) unsigned short u8v;
typedef __attribute__((ext_vector_type(4))) unsigned short u4v;
typedef __attribute__((ext_vector_type(4))) float f4v;

static inline int divup(int a, int b){ return (a+b-1)/b; }
static inline int imin(int a, int b){ return a < b ? a : b; }

__device__ __forceinline__ unsigned short bf16r(float x){
    unsigned int u = __float_as_uint(x);
    u += 0x7fffu + ((u >> 16) & 1u);       // round-to-nearest-even
    return (unsigned short)(u >> 16);
}
__device__ __forceinline__ float bf16f(unsigned short h){
    return __uint_as_float(((unsigned int)h) << 16);
}

// async global->LDS, 16B per lane; LDS dest = uniform base + lane*16
__device__ __forceinline__ void gload16(const unsigned short* g, unsigned short* l){
    __builtin_amdgcn_global_load_lds(
        (const __attribute__((address_space(1))) void*)g,
        (__attribute__((address_space(3))) void*)l, 16, 0, 0);
}

// ---------------------------------------------------------------------------
// decompose fp32 -> (hi, lo) bf16 pair: x = hi + lo + O(2^-17 x)
// ---------------------------------------------------------------------------
__global__ __launch_bounds__(256)
void decomp_kernel(const float* __restrict__ x, unsigned short* __restrict__ hi,
                   unsigned short* __restrict__ lo, long n4)
{
    for (long i = (long)blockIdx.x * 256 + threadIdx.x; i < n4; i += (long)gridDim.x * 256) {
        float4 v = ((const float4*)x)[i];
        float a[4] = {v.x, v.y, v.z, v.w};
        u4v h, l;
#pragma unroll
        for (int e = 0; e < 4; e++) {
            unsigned short hb = bf16r(a[e]);
            h[e] = hb;
            l[e] = bf16r(a[e] - bf16f(hb));
        }
        *(u4v*)(hi + i * 4) = h;
        *(u4v*)(lo + i * 4) = l;
    }
}

// ---------------------------------------------------------------------------
// Split-bf16 NT GEMM via MFMA: C[M,Nn] = alpha * A[M,Kk] * B[Nn,Kk]^T
// (unchanged from round 4 — 37.9% MfmaUtil, 0 bank conflicts, verified)
// ---------------------------------------------------------------------------
template<int OSPLIT, int STATS>
__global__ __launch_bounds__(256)
void gemm_split(const unsigned short* __restrict__ Ah, const unsigned short* __restrict__ Al,
                const unsigned short* __restrict__ Bh, const unsigned short* __restrict__ Bl,
                float* __restrict__ Cf, unsigned short* __restrict__ Ch,
                unsigned short* __restrict__ Cl, double* __restrict__ part,
                int M, int Nn, int Kk, int ldA, int ldB, int ldC,
                long sAb, long sAh_, long sBb, long sBh_, long sCb, long sCh_,
                int Hdiv, float alpha)
{
    __shared__ u8v AsV[128 * 8];
    __shared__ u8v BsV[128 * 8];
    unsigned short* As = (unsigned short*)AsV;
    unsigned short* Bs = (unsigned short*)BsV;

    int z  = blockIdx.z;
    int bb = z / Hdiv, hz = z - bb * Hdiv;
    const unsigned short* gah = Ah + (long)bb * sAb + (long)hz * sAh_;
    const unsigned short* gal = Al + (long)bb * sAb + (long)hz * sAh_;
    const unsigned short* gbh = Bh + (long)bb * sBb + (long)hz * sBh_;
    const unsigned short* gbl = Bl + (long)bb * sBb + (long)hz * sBh_;
    long coff = (long)bb * sCb + (long)hz * sCh_;

    int t = threadIdx.x;
    int m0 = blockIdx.y * 128, n0 = blockIdx.x * 128;
    int wave = t >> 6, lane = t & 63;
    int wm = wave >> 1, wn = wave & 1;
    int lr = lane & 15, lk = lane >> 4;

    int ls   = (lane & 7) ^ (lane >> 3);
    int comp = ls >> 2;
    int chnk = ls & 3;
    const unsigned short* gA = comp ? gal : gah;
    const unsigned short* gB = comp ? gbl : gbh;
    const unsigned short* aptr[4];
    const unsigned short* bptr[4];
#pragma unroll
    for (int j = 0; j < 4; j++) {
        int ra = m0 + wave * 32 + j * 8 + (lane >> 3);
        ra = (ra < M) ? ra : (M - 1);
        aptr[j] = gA + (long)ra * ldA + chnk * 8;
        int rb = n0 + wave * 32 + j * 8 + (lane >> 3);
        rb = (rb < Nn) ? rb : (Nn - 1);
        bptr[j] = gB + (long)rb * ldB + chnk * 8;
    }

    f4v acc[4][4];
#pragma unroll
    for (int i = 0; i < 4; i++)
#pragma unroll
        for (int j = 0; j < 4; j++) acc[i][j] = (f4v){0.f, 0.f, 0.f, 0.f};

    int nkt = Kk >> 5;
    for (int kt = 0; kt < nkt; ++kt) {
        int k0 = kt << 5;
#pragma unroll
        for (int j = 0; j < 4; j++) {
            gload16(aptr[j] + k0, As + (wave * 4 + j) * 512);
            gload16(bptr[j] + k0, Bs + (wave * 4 + j) * 512);
        }
        __syncthreads();

        s8v afh[4], afl[4], bfh[4], bfl[4];
#pragma unroll
        for (int i = 0; i < 4; i++) {
            int rw = wm * 64 + i * 16 + lr;
            afh[i] = *(const s8v*)&As[rw * 64 + ((lk ^ (rw & 7)) << 3)];
            afl[i] = *(const s8v*)&As[rw * 64 + (((lk + 4) ^ (rw & 7)) << 3)];
            int cw = wn * 64 + i * 16 + lr;
            bfh[i] = *(const s8v*)&Bs[cw * 64 + ((lk ^ (cw & 7)) << 3)];
            bfl[i] = *(const s8v*)&Bs[cw * 64 + (((lk + 4) ^ (cw & 7)) << 3)];
        }
#pragma unroll
        for (int i = 0; i < 4; i++)
#pragma unroll
            for (int j = 0; j < 4; j++) {
                acc[i][j] = __builtin_amdgcn_mfma_f32_16x16x32_bf16(afh[i], bfh[j], acc[i][j], 0, 0, 0);
                acc[i][j] = __builtin_amdgcn_mfma_f32_16x16x32_bf16(afl[i], bfh[j], acc[i][j], 0, 0, 0);
                acc[i][j] = __builtin_amdgcn_mfma_f32_16x16x32_bf16(afh[i], bfl[j], acc[i][j], 0, 0, 0);
            }
        __syncthreads();
    }

    float s1 = 0.f, s2 = 0.f;
#pragma unroll
    for (int i = 0; i < 4; i++)
#pragma unroll
        for (int j = 0; j < 4; j++)
#pragma unroll
            for (int r = 0; r < 4; r++) {
                int gr = m0 + wm * 64 + i * 16 + lk * 4 + r;
                int gc = n0 + wn * 64 + j * 16 + lr;
                if (gr < M) {
                    if (gc < Nn) {
                        float v = acc[i][j][r] * alpha;
                        if (STATS) { s1 += v; s2 += v * v; }
                        if (OSPLIT) {
                            unsigned short hb = bf16r(v);
                            Ch[coff + (long)gr * ldC + gc] = hb;
                            Cl[coff + (long)gr * ldC + gc] = bf16r(v - bf16f(hb));
                        } else {
                            Cf[coff + (long)gr * ldC + gc] = v;
                        }
                    } else if (OSPLIT && gc < ldC) {
                        Ch[coff + (long)gr * ldC + gc] = 0;
                        Cl[coff + (long)gr * ldC + gc] = 0;
                    }
                }
            }

    if (STATS) {
        double* sh = (double*)AsV;
        sh[t] = (double)s1; sh[256 + t] = (double)s2;
        __syncthreads();
        for (int o = 128; o > 0; o >>= 1) {
            if (t < o) { sh[t] += sh[t + o]; sh[256 + t] += sh[256 + t + o]; }
            __syncthreads();
        }
        if (t == 0) {
            atomicAdd(&part[z * 2 + 0], sh[0]);
            atomicAdd(&part[z * 2 + 1], sh[256]);
        }
    }
}

// ---------------------------------------------------------------------------
// Fused softmax+PV: ctx[c,196] = softmax_kv((S-mu)*is) @ V^T, per map.
// Softmax normalization commutes with PV: stage p=exp(s*is+d) (no max-sub:
// s~N(0,1) after instance-norm scale -> exp bounded ~e^6), accumulate per-row
// Z during staging, divide in epilogue. BM=64, BN=224 (196 used, single col
// block per row-tile so each row's Z is fully local to one block).
// grid: (1, c/64, g). V layout: [b][196][3840] (hz*960 col offset).
// ---------------------------------------------------------------------------
__global__ __launch_bounds__(256)
void pv_fused(const float* __restrict__ Sb, const unsigned short* __restrict__ Vh,
              const unsigned short* __restrict__ Vl, const double* __restrict__ part,
              float* __restrict__ Cb, int c, int m0)
{
    __shared__ unsigned short As[64 * 64];    // P tile: 64 rows x 32kv (hi|lo), XOR-swizzled
    __shared__ unsigned short Bs[224 * 64];   // V tile: 224 cols x 32kv (hi|lo)
    __shared__ float Zlds[64];
    __shared__ float bc2[2];

    int z  = blockIdx.z;
    int gm = m0 + z;                 // group-local map
    int bb = gm >> 2, hz = gm & 3;
    int my0 = blockIdx.y * 64;

    int t = threadIdx.x;
    int wave = t >> 6, lane = t & 63;
    int wm = wave >> 1, wn = wave & 1;
    int lr = lane & 15, lk = lane >> 4;

    if (t == 0) {
        double su = part[gm * 2 + 0], sq = part[gm * 2 + 1];
        float inv_e = 1.0f / (float)(c * KVD);
        float mean = (float)(su * (double)inv_e);
        float var  = (float)(sq * (double)inv_e) - mean * mean;
        float is   = rsqrtf(var + 1e-5f);
        bc2[0] = is; bc2[1] = -mean * is;
    }
    __syncthreads();
    float is = bc2[0], dd = bc2[1];

    // A (P) staging map: thread t -> row t>>2, 8-kv chunk t&3
    int arow = t >> 2, achk = t & 3;
    const float* sp = Sb + (size_t)z * c * KVD + (size_t)(my0 + arow) * KVD + achk * 8;
    unsigned short* awh = &As[arow * 64 + (( achk      ^ (arow & 7)) << 3)];
    unsigned short* awl = &As[arow * 64 + (((achk + 4) ^ (arow & 7)) << 3)];

    // B (V) staging: 7 gload16 per thread (224 rows x 128B)
    int ls   = (lane & 7) ^ (lane >> 3);
    int comp = ls >> 2, chnk = ls & 3;
    const unsigned short* vbase = (comp ? Vl : Vh) + (long)bb * (196L * 3840) + hz * 960;
    const unsigned short* bptr[7];
    unsigned short* bdst[7];
#pragma unroll
    for (int q = 0; q < 7; q++) {
        int rlog = (wave * 7 + q) * 8 + (lane >> 3);
        int vrow = (rlog < NP) ? rlog : (NP - 1);
        bptr[q] = vbase + (long)vrow * 3840 + chnk * 8;
        bdst[q] = &Bs[(wave * 7 + q) * 512];
    }

    f4v acc[2][7];
#pragma unroll
    for (int i = 0; i < 2; i++)
#pragma unroll
        for (int j = 0; j < 7; j++) acc[i][j] = (f4v){0.f, 0.f, 0.f, 0.f};
    float zp = 0.f;

    for (int kt = 0; kt < 30; ++kt) {
        int k0 = kt << 5;
#pragma unroll
        for (int q = 0; q < 7; q++) gload16(bptr[q] + k0, bdst[q]);

        float4 v0 = *(const float4*)(sp + k0);
        float4 v1 = *(const float4*)(sp + k0 + 4);
        float s[8] = {v0.x, v0.y, v0.z, v0.w, v1.x, v1.y, v1.z, v1.w};
        u8v hv, lv;
#pragma unroll
        for (int e = 0; e < 8; e++) {
            float p = __expf(fmaf(s[e], is, dd));
            zp += p;
            unsigned short hb = bf16r(p);
            hv[e] = hb;
            lv[e] = bf16r(p - bf16f(hb));
        }
        *(u8v*)awh = hv;
        *(u8v*)awl = lv;
        __syncthreads();

        s8v afh[2], afl[2], bfh[7], bfl[7];
#pragma unroll
        for (int i = 0; i < 2; i++) {
            int ar = wm * 32 + i * 16 + lr;
            afh[i] = *(const s8v*)&As[ar * 64 + ((lk ^ (ar & 7)) << 3)];
            afl[i] = *(const s8v*)&As[ar * 64 + (((lk + 4) ^ (ar & 7)) << 3)];
        }
#pragma unroll
        for (int j = 0; j < 7; j++) {
            int br = wn * 112 + j * 16 + lr;
            bfh[j] = *(const s8v*)&Bs[br * 64 + ((lk ^ (br & 7)) << 3)];
            bfl[j] = *(const s8v*)&Bs[br * 64 + (((lk + 4) ^ (br & 7)) << 3)];
        }
#pragma unroll
        for (int i = 0; i < 2; i++)
#pragma unroll
            for (int j = 0; j < 7; j++) {
                acc[i][j] = __builtin_amdgcn_mfma_f32_16x16x32_bf16(afh[i], bfh[j], acc[i][j], 0, 0, 0);
                acc[i][j] = __builtin_amdgcn_mfma_f32_16x16x32_bf16(afl[i], bfh[j], acc[i][j], 0, 0, 0);
                acc[i][j] = __builtin_amdgcn_mfma_f32_16x16x32_bf16(afh[i], bfl[j], acc[i][j], 0, 0, 0);
            }
        __syncthreads();
    }

    // per-row Z: 4 threads per row hold partials
    zp += __shfl_xor(zp, 1);
    zp += __shfl_xor(zp, 2);
    if ((t & 3) == 0) Zlds[arow] = zp;
    __syncthreads();

    float rz[2][4];
#pragma unroll
    for (int i = 0; i < 2; i++)
#pragma unroll
        for (int r = 0; r < 4; r++)
            rz[i][r] = 1.0f / Zlds[wm * 32 + i * 16 + lk * 4 + r];

    float* co = Cb + (size_t)gm * c * NP;
#pragma unroll
    for (int i = 0; i < 2; i++)
#pragma unroll
        for (int j = 0; j < 7; j++)
#pragma unroll
            for (int r = 0; r < 4; r++) {
                int grl = wm * 32 + i * 16 + lk * 4 + r;
                int gc  = wn * 112 + j * 16 + lr;
                if (gc < NP)
                    co[(size_t)(my0 + grl) * NP + gc] = acc[i][j][r] * rz[i][r];
            }
}

// ---------------------------------------------------------------------------
// head-mean + transpose: Mb[b,n,d] = 0.25 * sum_h Cb[(b*4+h), d, n], split out.
// ---------------------------------------------------------------------------
__global__ __launch_bounds__(256)
void mean_t_kernel(const float* __restrict__ Cb, unsigned short* __restrict__ Mh,
                   unsigned short* __restrict__ Ml, int c)
{
    int b  = blockIdx.z;
    int n0 = blockIdx.x * 32;
    int d0 = blockIdx.y * 32;
    __shared__ float tile[32][33];
    int tx = threadIdx.x & 31;
    int ty = threadIdx.x >> 5;
#pragma unroll
    for (int i = 0; i < 4; i++) {
        int d = d0 + ty + i * 8;
        int n = n0 + tx;
        float s = 0.f;
        if (n < NP) {
#pragma unroll
            for (int h = 0; h < HH; h++)
                s += Cb[(((long)(b * HH + h)) * c + d) * NP + n];
        }
        tile[ty + i * 8][tx] = 0.25f * s;
    }
    __syncthreads();
#pragma unroll
    for (int i = 0; i < 4; i++) {
        int n = n0 + ty + i * 8;
        int d = d0 + tx;
        if (n < NP) {
            float val = tile[tx][ty + i * 8];
            long idx = ((long)b * NP + n) * c + d;
            unsigned short hb = bf16r(val);
            Mh[idx] = hb;
            Ml[idx] = bf16r(val - bf16f(hb));
        }
    }
}

// ---------------------------------------------------------------------------
extern "C" void kernel_launch(void* const* d_in, const int* in_sizes, int n_in,
                              void* d_out, int out_size, void* d_ws, size_t ws_size,
                              hipStream_t stream)
{
    const float* embf[4] = {(const float*)d_in[0], (const float*)d_in[1],
                            (const float*)d_in[2], (const float*)d_in[3]};
    const float* emb_all = (const float*)d_in[4];
    const float* Wq[4]   = {(const float*)d_in[5], (const float*)d_in[6],
                            (const float*)d_in[7], (const float*)d_in[8]};
    const float* Wk = (const float*)d_in[9];
    const float* Wv = (const float*)d_in[10];
    const float* Wo[4]   = {(const float*)d_in[11], (const float*)d_in[12],
                            (const float*)d_in[13], (const float*)d_in[14]};
    float* out = (float*)d_out;

    const int Cc[4] = {64, 128, 256, 512};

    char* base = (char*)d_ws;
    size_t off = 0;
    auto carve = [&](size_t bytes) -> void* {
        void* p = base + off;
        off = (off + bytes + 255) & ~(size_t)255;
        return p;
    };

    const long NEA   = (long)BB * NP * KVD;
    const long NWKV  = (long)HH * KVD * KVD;
    const long SUMC2 = 64L*64 + 128L*128 + 256L*256 + 512L*512;

    // ---- fixed buffers ----
    unsigned short* wkH = (unsigned short*)carve(NWKV * 2);
    unsigned short* wkL = (unsigned short*)carve(NWKV * 2);
    unsigned short* wvH = (unsigned short*)carve(NWKV * 2);
    unsigned short* wvL = (unsigned short*)carve(NWKV * 2);
    unsigned short* wqH = (unsigned short*)carve((long)HH * SUMC2 * 2);
    unsigned short* wqL = (unsigned short*)carve((long)HH * SUMC2 * 2);
    unsigned short* woH = (unsigned short*)carve(SUMC2 * 2);
    unsigned short* woL = (unsigned short*)carve(SUMC2 * 2);
    unsigned short* eaH = (unsigned short*)carve(NEA * 2);
    unsigned short* eaL = (unsigned short*)carve(NEA * 2);
    double* part = (double*)carve(64L * 2 * 8);

    // ---- adaptive batch grouping ----
    size_t fixed_off = off;
    auto group_bytes = [&](int gb) -> size_t {
        long nbh = (long)gb * HH;
        size_t s = 0;
        auto add = [&](size_t b){ s += (b + 255) & ~(size_t)255; };
        add(nbh * KVD * KP * 2); add(nbh * KVD * KP * 2);    // Kt hi/lo
        add((long)gb * NP * HH * KVD * 2); add((long)gb * NP * HH * KVD * 2); // V hi/lo
        add(nbh * 512 * KP * 2); add(nbh * 512 * KP * 2);    // Qt hi/lo
        add(nbh * 512 * NP * 4);                             // Cb fp32
        add((long)gb * NP * 512 * 2); add((long)gb * NP * 512 * 2); // ei hi/lo
        add((long)gb * NP * 512 * 2); add((long)gb * NP * 512 * 2); // Mb hi/lo
        return s;
    };
    const size_t minchunk = (size_t)512 * KVD * 4 + (1 << 20);
    int GB = 16;
    while (GB > 1 && fixed_off + group_bytes(GB) + minchunk > ws_size) GB >>= 1;
    const long NBH = (long)GB * HH;

    unsigned short* KtH = (unsigned short*)carve(NBH * KVD * KP * 2);       // [b][3840][224]
    unsigned short* KtL = (unsigned short*)carve(NBH * KVD * KP * 2);
    unsigned short* VH  = (unsigned short*)carve((long)GB * NP * HH * KVD * 2); // [b][196][3840]
    unsigned short* VL  = (unsigned short*)carve((long)GB * NP * HH * KVD * 2);
    unsigned short* QtH = (unsigned short*)carve(NBH * 512 * KP * 2);       // [b][4c][224]
    unsigned short* QtL = (unsigned short*)carve(NBH * 512 * KP * 2);
    float*  Cb          = (float*)carve(NBH * 512 * NP * 4);                // [bh][c][196]
    unsigned short* eiH = (unsigned short*)carve((long)GB * NP * 512 * 2);
    unsigned short* eiL = (unsigned short*)carve((long)GB * NP * 512 * 2);
    unsigned short* MbH = (unsigned short*)carve((long)GB * NP * 512 * 2);
    unsigned short* MbL = (unsigned short*)carve((long)GB * NP * 512 * 2);

    size_t savail = (ws_size > off) ? (ws_size - off) : 0;
    char* chunk = base + off;

    dim3 blk(256);
    const float alphaS = 1.0f / sqrtf((float)KVD);

    auto dec = [&](const float* x, unsigned short* h, unsigned short* l, long n) {
        long n4 = n / 4;
        int g = (int)((n4 + 255) / 256);
        if (g > 1024) g = 1024;
        decomp_kernel<<<g, blk, 0, stream>>>(x, h, l, n4);
    };

    // ---- decompose weights + emb_all once ----
    dec(emb_all, eaH, eaL, NEA);
    long wqo[4], woo[4];
    long qo = 0, oo = 0;
    for (int i = 0; i < 4; i++) {
        wqo[i] = qo; dec(Wq[i], wqH + qo, wqL + qo, (long)HH * Cc[i] * Cc[i]);
        qo += (long)HH * Cc[i] * Cc[i];
        woo[i] = oo; dec(Wo[i], woH + oo, woL + oo, (long)Cc[i] * Cc[i]);
        oo += (long)Cc[i] * Cc[i];
    }
    dec(Wk, wkH, wkL, NWKV);
    dec(Wv, wvH, wvL, NWKV);

    long obase[4];
    { long o = 0; for (int i = 0; i < 4; i++) { obase[i] = o; o += (long)BB * NP * Cc[i]; } }

    // ---- batch-group passes ----
    for (int g0 = 0; g0 < BB; g0 += GB) {
        const unsigned short* eaHg = eaH + (long)g0 * NP * KVD;
        const unsigned short* eaLg = eaL + (long)g0 * NP * KVD;

        // Kt[b][3840][224] = Wk_all @ emb_all[b]^T  (heads merged into M)
        gemm_split<1,0><<<dim3(2, 30, GB), blk, 0, stream>>>(
            wkH, wkL, eaHg, eaLg, nullptr, KtH, KtL, nullptr,
            HH * KVD, NP, KVD, KVD, KVD, KP,
            0, 0, (long)NP * KVD, 0,
            (long)HH * KVD * KP, 0, 1, 1.0f);

        // V[b][196][3840] = emb_all[b] @ Wv_all^T  (heads merged into N)
        gemm_split<1,0><<<dim3(30, 2, GB), blk, 0, stream>>>(
            eaHg, eaLg, wvH, wvL, nullptr, VH, VL, nullptr,
            NP, HH * KVD, KVD, KVD, KVD, HH * KVD,
            (long)NP * KVD, 0, 0, 0,
            (long)NP * HH * KVD, 0, 1, 1.0f);

        for (int i = 0; i < 4; i++) {
            int c = Cc[i];
            dec(embf[i] + (long)g0 * NP * c, eiH, eiL, (long)GB * NP * c);

            // Qt[b][4c][224] = Wq_all_i @ emb_i[b]^T  (heads merged into M)
            gemm_split<1,0><<<dim3(2, divup(HH * c, 128), GB), blk, 0, stream>>>(
                wqH + wqo[i], wqL + wqo[i], eiH, eiL, nullptr, QtH, QtL, nullptr,
                HH * c, NP, c, c, c, KP,
                0, 0, (long)NP * c, 0,
                (long)HH * c * KP, 0, 1, 1.0f);

            hipMemsetAsync(part, 0, 64 * 2 * sizeof(double), stream);

            size_t per = (size_t)c * KVD * 4;   // S fp32 per map
            int G = (savail >= per) ? (int)(savail / per) : 1;
            if (G > (int)NBH) G = (int)NBH;
            if (G < 1) G = 1;
            float* Sb = (float*)chunk;

            for (int m0 = 0; m0 < (int)NBH; m0 += G) {
                int g = imin(G, (int)NBH - m0);
                // S[c,960] = (Qt @ Kt^T)/sqrt(960), K padded to 224; fused stats
                gemm_split<0,1><<<dim3(8, divup(c, 128), g), blk, 0, stream>>>(
                    QtH + (size_t)m0 * c * KP, QtL + (size_t)m0 * c * KP,
                    KtH + (size_t)m0 * KVD * KP, KtL + (size_t)m0 * KVD * KP,
                    Sb, nullptr, nullptr, part + (size_t)m0 * 2,
                    c, KVD, KP, KP, KP, KVD,
                    (long)c * KP, 0, (long)KVD * KP, 0, (long)c * KVD, 0,
                    1, alphaS);
                // fused exp/Z/PV -> ctx fp32
                pv_fused<<<dim3(1, c / 64, g), blk, 0, stream>>>(
                    Sb, VH, VL, part, Cb, c, m0);
            }
            // head-mean + transpose -> split Mb[b_local,n,d]
            mean_t_kernel<<<dim3(divup(NP, 32), c / 32, GB), blk, 0, stream>>>(Cb, MbH, MbL, c);
            // O rows for this group = Mb @ Wo^T
            gemm_split<0,0><<<dim3(divup(c, 128), divup(GB * NP, 128), 1), blk, 0, stream>>>(
                MbH, MbL, woH + woo[i], woL + woo[i],
                out + obase[i] + (long)g0 * NP * c, nullptr, nullptr, nullptr,
                GB * NP, c, c, c, c, c,
                0, 0, 0, 0, 0, 0, 1, 1.0f);
        }
    }
}